// Round 1
// baseline (229.861 us; speedup 1.0000x reference)
//
#include <hip/hip_runtime.h>
#include <hip/hip_bf16.h>

#define TOKENS  2048
#define IN_DIM  4096
#define OUT_DIM 11008
#define NGROUPS 32

// ---- i8 GEMM geometry: 128x128 tile, BK=128 (= 1 scale group), 32x32x32 MFMA,
//      4 waves (64x64 each), 2 blocks/CU, deferred dequant-accum ----
#define BM 128
#define BN 128
#define BKB 128                // i8 elems (=bytes) per row per K-tile = one quant group
#define THREADS 256
#define NKT   (IN_DIM / BKB)   // 32 K-tiles
#define BUFB  32768            // bytes per LDS buffer (A 16KB + B 16KB)
#define BOFF  16384            // B region offset within buffer

using f32x4  = __attribute__((ext_vector_type(4))) float;
using i32x4  = __attribute__((ext_vector_type(4))) int;
using i32x16 = __attribute__((ext_vector_type(16))) int;
using bf16x8 = __attribute__((ext_vector_type(8))) short;

typedef __attribute__((address_space(3))) char as3c;

static __device__ __forceinline__ short f2bf(float f) {
    union { float f; unsigned u; } v; v.f = f;
    unsigned r = v.u + 0x7FFFu + ((v.u >> 16) & 1u);
    return (short)(r >> 16);
}

static __device__ __forceinline__ int pack4(int a, int b, int c, int d) {
    return (a & 255) | ((b & 255) << 8) | ((c & 255) << 16) | ((d & 255) << 24);
}

#define SB0 __builtin_amdgcn_sched_barrier(0)
#define LDSRO(dst, addr, off) asm volatile("ds_read_b128 %0, %1 offset:" #off : "=v"(dst) : "v"(addr))
#define WAITL(n) do { asm volatile("s_waitcnt lgkmcnt(" #n ")"); SB0; } while (0)
#define WAITV(n) do { asm volatile("s_waitcnt vmcnt(" #n ")");  SB0; } while (0)

// ---- pass 0a: per-token i8 quant of x/s; sx[row] = max|x/s| / 127 ----
__global__ __launch_bounds__(256) void prep_a_kernel(
    const float* __restrict__ x, const float* __restrict__ s,
    char* __restrict__ Aq, float* __restrict__ sx)
{
    const int row = blockIdx.x, t = threadIdx.x;
    const float* xp = x + (size_t)row * IN_DIM + t * 16;
    const float* sp = s + t * 16;
    f32x4 v[4];
    float m = 0.f;
    #pragma unroll
    for (int q = 0; q < 4; ++q) {
        f32x4 xv = *(const f32x4*)(xp + q * 4);
        f32x4 sv = *(const f32x4*)(sp + q * 4);
        #pragma unroll
        for (int e = 0; e < 4; ++e) {
            v[q][e] = xv[e] / sv[e];
            m = fmaxf(m, fabsf(v[q][e]));
        }
    }
    #pragma unroll
    for (int off = 32; off; off >>= 1) m = fmaxf(m, __shfl_xor(m, off));
    __shared__ float wm[4];
    if ((t & 63) == 0) wm[t >> 6] = m;
    __syncthreads();
    m = fmaxf(fmaxf(wm[0], wm[1]), fmaxf(wm[2], wm[3]));
    m = fmaxf(m, 1e-20f);
    const float inv = 127.0f / m;
    i32x4 pk;
    #pragma unroll
    for (int q = 0; q < 4; ++q)
        pk[q] = pack4((int)rintf(v[q][0] * inv), (int)rintf(v[q][1] * inv),
                      (int)rintf(v[q][2] * inv), (int)rintf(v[q][3] * inv));
    ((i32x4*)(Aq + (size_t)row * IN_DIM))[t] = pk;
    if (t == 0) sx[row] = m * (1.0f / 127.0f);
}

// ---- pass 0b: w_q i32 -> i8 (exact) ----
__global__ __launch_bounds__(256) void prep_b_kernel(
    const int* __restrict__ wq, char* __restrict__ Bq)
{
    const int idx = blockIdx.x * 256 + threadIdx.x;   // 16 elems each
    const int* wp = wq + (size_t)idx * 16;
    i32x4 w0 = *(const i32x4*)wp, w1 = *(const i32x4*)(wp + 4);
    i32x4 w2 = *(const i32x4*)(wp + 8), w3 = *(const i32x4*)(wp + 12);
    i32x4 pk;
    pk[0] = pack4(w0[0], w0[1], w0[2], w0[3]);
    pk[1] = pack4(w1[0], w1[1], w1[2], w1[3]);
    pk[2] = pack4(w2[0], w2[1], w2[2], w2[3]);
    pk[3] = pack4(w3[0], w3[1], w3[2], w3[3]);
    ((i32x4*)Bq)[idx] = pk;
}

// ---- pass 0c: transpose scales [O][G] -> scT [G][O] ----
__global__ __launch_bounds__(256) void prep_sc_kernel(
    const float* __restrict__ scales, float* __restrict__ scT)
{
    const int idx = blockIdx.x * 256 + threadIdx.x;
    const int g = idx / OUT_DIM;
    const int o = idx - g * OUT_DIM;
    scT[idx] = scales[o * NGROUPS + g];
}

// ---- 128x128 i8 GEMM, 32x32x32 MFMA, 64x64 per-wave, 2 blocks/CU ----
__global__ __launch_bounds__(THREADS, 2) void awq_gemm_i8(
    const char* __restrict__ Aq, const char* __restrict__ Bq,
    const float* __restrict__ scT, const float* __restrict__ sx,
    const float* __restrict__ bias, float* __restrict__ out)
{
    // per-XCD block map (rb&7 -> XCD round-robin)
    const int rb = blockIdx.x;                  // grid 1408 = 8 * 176
    const int bm = (rb >> 3) & 15;              // 0..15
    const int bn = (((rb >> 3) >> 4) << 3) + (rb & 7);  // 0..87
    if (bn >= OUT_DIM / BN) return;             // 32 dead pad blocks

    __shared__ char smem[2 * BUFB];             // 64 KB -> 2 blocks/CU
    as3c* ldsb = (as3c*)smem;
    const unsigned lbase = (unsigned)(size_t)ldsb;

    const int tid  = threadIdx.x;
    const int lane = tid & 63;
    const int w    = tid >> 6;        // wave 0..3
    const int wr   = w >> 1;          // 0..1 (M: 2 x 64)
    const int wc   = w & 1;           // 0..1 (N: 2 x 64)
    const int lr   = lane & 31;       // frag row (A) / col (B)
    const int hi   = lane >> 5;       // k-half within 32-elem k-chunk
    const int h7   = lr & 7;

    // per-kk swizzled ds_read bases (buffer 0); granule slot g holds global granule g^(row&7)
    const unsigned aRow = lbase + (unsigned)((wr * 64 + lr) * 128);
    const unsigned bRow = lbase + BOFF + (unsigned)((wc * 64 + lr) * 128);
    const unsigned aS0 = aRow + (unsigned)(((0 + hi) ^ h7) * 16);
    const unsigned aS1 = aRow + (unsigned)(((2 + hi) ^ h7) * 16);
    const unsigned aS2 = aRow + (unsigned)(((4 + hi) ^ h7) * 16);
    const unsigned aS3 = aRow + (unsigned)(((6 + hi) ^ h7) * 16);
    const unsigned bS0 = bRow + (unsigned)(((0 + hi) ^ h7) * 16);
    const unsigned bS1 = bRow + (unsigned)(((2 + hi) ^ h7) * 16);
    const unsigned bS2 = bRow + (unsigned)(((4 + hi) ^ h7) * 16);
    const unsigned bS3 = bRow + (unsigned)(((6 + hi) ^ h7) * 16);

    // staging: thread -> row tid>>3 (0..31) per sweep, granule tid&7 pre-swizzled
    const int srow = tid >> 3;
    const int sg   = ((tid & 7) ^ (srow & 7)) * 16;
    const char* aSrc = Aq + (size_t)(bm * BM + srow) * IN_DIM + sg;
    const char* bSrc = Bq + (size_t)(bn * BN + srow) * IN_DIM + sg;

    // scale source: per-lane column; +32 floats for j=1
    const float* scp = scT + bn * BN + wc * 64 + lr;

#define STG_A(Q, SRC, P) __builtin_amdgcn_global_load_lds( \
    (const __attribute__((address_space(1))) void*)(const void*)((SRC) + (size_t)((Q) * 32) * IN_DIM), \
    (__attribute__((address_space(3))) void*)(ldsb + (P) * BUFB + (Q) * 4096 + tid * 16), 16, 0, 0)
#define STG_B(Q, SRC, P) __builtin_amdgcn_global_load_lds( \
    (const __attribute__((address_space(1))) void*)(const void*)((SRC) + (size_t)((Q) * 32) * IN_DIM), \
    (__attribute__((address_space(3))) void*)(ldsb + (P) * BUFB + BOFF + (Q) * 4096 + tid * 16), 16, 0, 0)

#define SCV(D0, D1, PTR) do { \
    asm volatile("global_load_dword %0, %1, off" : "=v"(D0) : "v"(PTR)); \
    asm volatile("global_load_dword %0, %1, off" : "=v"(D1) : "v"((PTR) + 32)); \
    SB0; } while (0)

    float accf[2][2][16];
    #pragma unroll
    for (int i = 0; i < 2; ++i)
        #pragma unroll
        for (int j = 0; j < 2; ++j)
            #pragma unroll
            for (int e = 0; e < 16; ++e) accf[i][j][e] = 0.f;

    i32x16 acc[2][2];
    const i32x16 Z = {0,0,0,0,0,0,0,0,0,0,0,0,0,0,0,0};

    float c0, c1, n0 = 0.f, n1 = 0.f, p0 = 0.f, p1 = 0.f;

    // prologue ledger: S0[8], V0[2], S1[8] -> WAITV(8) retires S0+V0, keeps S1
    STG_A(0, aSrc, 0); STG_A(1, aSrc, 0); STG_A(2, aSrc, 0); STG_A(3, aSrc, 0);
    STG_B(0, bSrc, 0); STG_B(1, bSrc, 0); STG_B(2, bSrc, 0); STG_B(3, bSrc, 0);
    SCV(c0, c1, scp);
    STG_A(0, aSrc + BKB, 1); STG_A(1, aSrc + BKB, 1); STG_A(2, aSrc + BKB, 1); STG_A(3, aSrc + BKB, 1);
    STG_B(0, bSrc + BKB, 1); STG_B(1, bSrc + BKB, 1); STG_B(2, bSrc + BKB, 1); STG_B(3, bSrc + BKB, 1);
    WAITV(8);
    __builtin_amdgcn_s_barrier();
    SB0;

    const char* aStg = aSrc + 2 * BKB;   // staging column for tile t+2
    const char* bStg = bSrc + 2 * BKB;
    const float* scN = scp + OUT_DIM;    // scales for group t+1

    for (int t = 0; t < NKT; ++t) {
        const unsigned po = (unsigned)((t & 1) * BUFB);
        i32x4 a[2][4], b[2][4];
        const unsigned pa0 = aS0 + po, pa1 = aS1 + po, pa2 = aS2 + po, pa3 = aS3 + po;
        const unsigned pb0 = bS0 + po, pb1 = bS1 + po, pb2 = bS2 + po, pb3 = bS3 + po;
        // 16 ds_reads of tile t from buf P, kk-major (4 per kk group)
        LDSRO(a[0][0], pa0, 0); LDSRO(a[1][0], pa0, 4096);
        LDSRO(b[0][0], pb0, 0); LDSRO(b[1][0], pb0, 4096);
        LDSRO(a[0][1], pa1, 0); LDSRO(a[1][1], pa1, 4096);
        LDSRO(b[0][1], pb1, 0); LDSRO(b[1][1], pb1, 4096);
        LDSRO(a[0][2], pa2, 0); LDSRO(a[1][2], pa2, 4096);
        LDSRO(b[0][2], pb2, 0); LDSRO(b[1][2], pb2, 4096);
        LDSRO(a[0][3], pa3, 0); LDSRO(a[1][3], pa3, 4096);
        LDSRO(b[0][3], pb3, 0); LDSRO(b[1][3], pb3, 4096);

        // deferred dequant-accumulate of tile t-1: VALU overlaps the reads above
        if (t > 0) {
            #pragma unroll
            for (int i = 0; i < 2; ++i)
                #pragma unroll
                for (int e = 0; e < 16; ++e) {
                    accf[i][0][e] += (float)acc[i][0][e] * p0;
                    accf[i][1][e] += (float)acc[i][1][e] * p1;
                }
        }

        __builtin_amdgcn_s_setprio(1);
        WAITL(12);   // kk0 reads landed
        acc[0][0] = __builtin_amdgcn_mfma_i32_32x32x32_i8(a[0][0], b[0][0], Z, 0, 0, 0);
        acc[0][1] = __builtin_amdgcn_mfma_i32_32x32x32_i8(a[0][0], b[1][0], Z, 0, 0, 0);
        acc[1][0] = __builtin_amdgcn_mfma_i32_32x32x32_i8(a[1][0], b[0][0], Z, 0, 0, 0);
        acc[1][1] = __builtin_amdgcn_mfma_i32_32x32x32_i8(a[1][0], b[1][0], Z, 0, 0, 0);
        WAITL(8);    // kk1
        acc[0][0] = __builtin_amdgcn_mfma_i32_32x32x32_i8(a[0][1], b[0][1], acc[0][0], 0, 0, 0);
        acc[0][1] = __builtin_amdgcn_mfma_i32_32x32x32_i8(a[0][1], b[1][1], acc[0][1], 0, 0, 0);
        acc[1][0] = __builtin_amdgcn_mfma_i32_32x32x32_i8(a[1][1], b[0][1], acc[1][0], 0, 0, 0);
        acc[1][1] = __builtin_amdgcn_mfma_i32_32x32x32_i8(a[1][1], b[1][1], acc[1][1], 0, 0, 0);
        WAITL(4);    // kk2
        acc[0][0] = __builtin_amdgcn_mfma_i32_32x32x32_i8(a[0][2], b[0][2], acc[0][0], 0, 0, 0);
        acc[0][1] = __builtin_amdgcn_mfma_i32_32x32x32_i8(a[0][2], b[1][2], acc[0][1], 0, 0, 0);
        acc[1][0] = __builtin_amdgcn_mfma_i32_32x32x32_i8(a[1][2], b[0][2], acc[1][0], 0, 0, 0);
        acc[1][1] = __builtin_amdgcn_mfma_i32_32x32x32_i8(a[1][2], b[1][2], acc[1][1], 0, 0, 0);
        WAITL(0);    // all 16 reads done for THIS wave
        __builtin_amdgcn_s_barrier();   // all waves done reading buf P -> safe to restage it
        SB0;
        acc[0][0] = __builtin_amdgcn_mfma_i32_32x32x32_i8(a[0][3], b[0][3], acc[0][0], 0, 0, 0);
        acc[0][1] = __builtin_amdgcn_mfma_i32_32x32x32_i8(a[0][3], b[1][3], acc[0][1], 0, 0, 0);
        acc[1][0] = __builtin_amdgcn_mfma_i32_32x32x32_i8(a[1][3], b[0][3], acc[1][0], 0, 0, 0);
        acc[1][1] = __builtin_amdgcn_mfma_i32_32x32x32_i8(a[1][3], b[1][3], acc[1][1], 0, 0, 0);
        __builtin_amdgcn_s_setprio(0);

        // prefetch next-group scales, then stage tile t+2 into the freed buf P
        const bool haveN = (t + 1 < NKT);
        if (haveN) SCV(n0, n1, scN);
        if (t + 2 < NKT) {
            STG_A(0, aStg, (t & 1)); STG_A(1, aStg, (t & 1)); STG_A(2, aStg, (t & 1)); STG_A(3, aStg, (t & 1));
            STG_B(0, bStg, (t & 1)); STG_B(1, bStg, (t & 1)); STG_B(2, bStg, (t & 1)); STG_B(3, bStg, (t & 1));
        }
        aStg += BKB; bStg += BKB; scN += OUT_DIM;

        // gate: steady state retires S(t+1)[8]+V(t+1)[2], keeps S(t+2)[8]
        if (t < NKT - 2) { WAITV(8); } else { WAITV(0); }
        __builtin_amdgcn_s_barrier();
        SB0;
        p0 = c0; p1 = c1;                  // scales for the now-pending tile t
        if (haveN) { c0 = n0; c1 = n1; }   // V(t+1) retired at the gate
    }

    // final dequant-accumulate (tile NKT-1)
    #pragma unroll
    for (int i = 0; i < 2; ++i)
        #pragma unroll
        for (int e = 0; e < 16; ++e) {
            accf[i][0][e] += (float)acc[i][0][e] * p0;
            accf[i][1][e] += (float)acc[i][1][e] * p1;
        }

    // ---- epilogue: * sx[row], + bias[col] ----
    // C/D 32x32 layout: col = lane&31, row = (reg&3) + 8*(reg>>2) + 4*(lane>>5)
    const int colBase = bn * BN + wc * 64 + lr;
    const float bv0 = bias[colBase];
    const float bv1 = bias[colBase + 32];
    #pragma unroll
    for (int i = 0; i < 2; ++i) {
        #pragma unroll
        for (int q = 0; q < 4; ++q) {
            const int r0 = bm * BM + wr * 64 + i * 32 + q * 8 + hi * 4;
            const f32x4 sxv = *(const f32x4*)(sx + r0);
            #pragma unroll
            for (int e = 0; e < 4; ++e) {
                out[(size_t)(r0 + e) * OUT_DIM + colBase]      = accf[i][0][q * 4 + e] * sxv[e] + bv0;
                out[(size_t)(r0 + e) * OUT_DIM + colBase + 32] = accf[i][1][q * 4 + e] * sxv[e] + bv1;
            }
        }
    }

#undef STG_A
#undef STG_B
#undef SCV
}

// ---- fallback (no workspace): round-1 proven kernel ----
__global__ __launch_bounds__(256) void awq_gemm_fb(
    const float* __restrict__ x, const int* __restrict__ wq,
    const float* __restrict__ scales, const float* __restrict__ s,
    const float* __restrict__ bias, float* __restrict__ out)
{
    __shared__ short As[128][32];
    __shared__ short Bs[128][32];
    const int tid = threadIdx.x, lane = tid & 63, wave = tid >> 6;
    const int nbn = OUT_DIM / 128;
    const int bm = blockIdx.x / nbn, bn = blockIdx.x % nbn;
    const int srow = tid >> 1, scol = (tid & 1) * 16;
    const int wm = (wave >> 1) * 64, wn = (wave & 1) * 64;
    f32x4 acc[4][4];
    #pragma unroll
    for (int i = 0; i < 4; ++i)
        #pragma unroll
        for (int j = 0; j < 4; ++j) acc[i][j] = (f32x4){0.f, 0.f, 0.f, 0.f};
    const float* xrow = x + (size_t)(bm * 128 + srow) * IN_DIM;
    const int* wrow = wq + (size_t)(bn * 128 + srow) * IN_DIM;
    const float* scrow = scales + (size_t)(bn * 128 + srow) * NGROUPS;
    const int fr = lane & 15, fk = (lane >> 4) * 8, fq = lane >> 4;
    for (int kt = 0; kt < IN_DIM / 32; ++kt) {
        const int k0 = kt * 32;
        {
            const float* xp = xrow + k0 + scol;
            const float* sp = s + k0 + scol;
            short tmp[16];
            #pragma unroll
            for (int q = 0; q < 4; ++q) {
                f32x4 xv = *(const f32x4*)(xp + q * 4);
                f32x4 sv = *(const f32x4*)(sp + q * 4);
                #pragma unroll
                for (int e = 0; e < 4; ++e) tmp[q * 4 + e] = f2bf(xv[e] / sv[e]);
            }
            #pragma unroll
            for (int e = 0; e < 16; ++e) As[srow][scol + e] = tmp[e];
        }
        {
            const float sc = scrow[kt >> 2];
            const int* wp = wrow + k0 + scol;
            short tmp[16];
            #pragma unroll
            for (int q = 0; q < 4; ++q) {
                i32x4 wv = *(const i32x4*)(wp + q * 4);
                #pragma unroll
                for (int e = 0; e < 4; ++e) tmp[q * 4 + e] = f2bf((float)wv[e] * sc);
            }
            #pragma unroll
            for (int e = 0; e < 16; ++e) Bs[srow][scol + e] = tmp[e];
        }
        __syncthreads();
        bf16x8 a[4], b[4];
        #pragma unroll
        for (int i = 0; i < 4; ++i) a[i] = *(const bf16x8*)&As[wm + i * 16 + fr][fk];
        #pragma unroll
        for (int j = 0; j < 4; ++j) b[j] = *(const bf16x8*)&Bs[wn + j * 16 + fr][fk];
        #pragma unroll
        for (int i = 0; i < 4; ++i)
            #pragma unroll
            for (int j = 0; j < 4; ++j)
                acc[i][j] = __builtin_amdgcn_mfma_f32_16x16x32_bf16(a[i], b[j], acc[i][j], 0, 0, 0);
        __syncthreads();
    }
    #pragma unroll
    for (int i = 0; i < 4; ++i) {
        const int row = bm * 128 + wm + i * 16 + fq * 4;
        #pragma unroll
        for (int j = 0; j < 4; ++j) {
            const int col = bn * 128 + wn + j * 16 + fr;
            const float bv = bias[col];
            #pragma unroll
            for (int e = 0; e < 4; ++e)
                out[(size_t)(row + e) * OUT_DIM + col] = acc[i][j][e] + bv;
        }
    }
}

extern "C" void kernel_launch(void* const* d_in, const int* in_sizes, int n_in,
                              void* d_out, int out_size, void* d_ws, size_t ws_size,
                              hipStream_t stream) {
    const float* x      = (const float*)d_in[0];
    const int*   wq     = (const int*)  d_in[1];
    const float* scales = (const float*)d_in[2];
    const float* s      = (const float*)d_in[3];
    const float* bias   = (const float*)d_in[4];
    float* out = (float*)d_out;

    // ws layout (16B-aligned): Aq 8MB | sx 8KB | Bq 43MB | scT 1.4MB
    const size_t off_sx = (size_t)TOKENS * IN_DIM;             // 8388608
    const size_t off_bq = off_sx + 8192;
    const size_t off_sc = off_bq + (size_t)OUT_DIM * IN_DIM;
    const size_t need   = off_sc + (size_t)OUT_DIM * NGROUPS * 4;  // ~54.9MB

    if (ws_size >= need) {
        char*  Aq  = (char*)d_ws;
        float* sxw = (float*)((char*)d_ws + off_sx);
        char*  Bq  = (char*)d_ws + off_bq;
        float* scT = (float*)((char*)d_ws + off_sc);
        prep_a_kernel<<<TOKENS, 256, 0, stream>>>(x, s, Aq, sxw);
        prep_b_kernel<<<OUT_DIM * IN_DIM / 16 / 256, 256, 0, stream>>>(wq, Bq);
        prep_sc_kernel<<<OUT_DIM * NGROUPS / 256, 256, 0, stream>>>(scales, scT);
        awq_gemm_i8<<<1408, THREADS, 0, stream>>>(Aq, Bq, scT, sxw, bias, out);
    } else {
        awq_gemm_fb<<<(TOKENS / 128) * (OUT_DIM / 128), 256, 0, stream>>>(x, wq, scales, s, bias, out);
    }
}

// Round 2
// 223.494 us; speedup vs baseline: 1.0285x; 1.0285x over previous
//
#include <hip/hip_runtime.h>
#include <hip/hip_bf16.h>

#define TOKENS  2048
#define IN_DIM  4096
#define OUT_DIM 11008
#define NGROUPS 32

// ---- i8 GEMM geometry: 128x128 tile, BK=128 (= 1 scale group), 32x32x32 MFMA,
//      4 waves (64x64 each), 2 blocks/CU, deferred dequant-accum ----
#define BM 128
#define BN 128
#define BKB 128                // i8 elems (=bytes) per row per K-tile = one quant group
#define THREADS 256
#define NKT   (IN_DIM / BKB)   // 32 K-tiles
#define BUFB  32768            // bytes per LDS buffer (A 16KB + B 16KB)
#define BOFF  16384            // B region offset within buffer

using f32x4  = __attribute__((ext_vector_type(4))) float;
using i32x4  = __attribute__((ext_vector_type(4))) int;
using i32x16 = __attribute__((ext_vector_type(16))) int;
using bf16x8 = __attribute__((ext_vector_type(8))) short;

typedef __attribute__((address_space(3))) char as3c;

static __device__ __forceinline__ short f2bf(float f) {
    union { float f; unsigned u; } v; v.f = f;
    unsigned r = v.u + 0x7FFFu + ((v.u >> 16) & 1u);
    return (short)(r >> 16);
}

static __device__ __forceinline__ int pack4(int a, int b, int c, int d) {
    return (a & 255) | ((b & 255) << 8) | ((c & 255) << 16) | ((d & 255) << 24);
}

#define SB0 __builtin_amdgcn_sched_barrier(0)
#define LDSRO(dst, addr, off) asm volatile("ds_read_b128 %0, %1 offset:" #off : "=v"(dst) : "v"(addr))
#define WAITL(n) do { asm volatile("s_waitcnt lgkmcnt(" #n ")"); SB0; } while (0)
#define WAITV(n) do { asm volatile("s_waitcnt vmcnt(" #n ")");  SB0; } while (0)

// ---- pass 0a: per-token i8 quant of x/s; sx[row] = max|x/s| / 127 ----
__global__ __launch_bounds__(256) void prep_a_kernel(
    const float* __restrict__ x, const float* __restrict__ s,
    char* __restrict__ Aq, float* __restrict__ sx)
{
    const int row = blockIdx.x, t = threadIdx.x;
    const float* xp = x + (size_t)row * IN_DIM + t * 16;
    const float* sp = s + t * 16;
    f32x4 v[4];
    float m = 0.f;
    #pragma unroll
    for (int q = 0; q < 4; ++q) {
        f32x4 xv = *(const f32x4*)(xp + q * 4);
        f32x4 sv = *(const f32x4*)(sp + q * 4);
        #pragma unroll
        for (int e = 0; e < 4; ++e) {
            v[q][e] = xv[e] / sv[e];
            m = fmaxf(m, fabsf(v[q][e]));
        }
    }
    #pragma unroll
    for (int off = 32; off; off >>= 1) m = fmaxf(m, __shfl_xor(m, off));
    __shared__ float wm[4];
    if ((t & 63) == 0) wm[t >> 6] = m;
    __syncthreads();
    m = fmaxf(fmaxf(wm[0], wm[1]), fmaxf(wm[2], wm[3]));
    m = fmaxf(m, 1e-20f);
    const float inv = 127.0f / m;
    i32x4 pk;
    #pragma unroll
    for (int q = 0; q < 4; ++q)
        pk[q] = pack4((int)rintf(v[q][0] * inv), (int)rintf(v[q][1] * inv),
                      (int)rintf(v[q][2] * inv), (int)rintf(v[q][3] * inv));
    ((i32x4*)(Aq + (size_t)row * IN_DIM))[t] = pk;
    if (t == 0) sx[row] = m * (1.0f / 127.0f);
}

// ---- pass 0b: w_q i32 -> i8 (exact) ----
__global__ __launch_bounds__(256) void prep_b_kernel(
    const int* __restrict__ wq, char* __restrict__ Bq)
{
    const int idx = blockIdx.x * 256 + threadIdx.x;   // 16 elems each
    const int* wp = wq + (size_t)idx * 16;
    i32x4 w0 = *(const i32x4*)wp, w1 = *(const i32x4*)(wp + 4);
    i32x4 w2 = *(const i32x4*)(wp + 8), w3 = *(const i32x4*)(wp + 12);
    i32x4 pk;
    pk[0] = pack4(w0[0], w0[1], w0[2], w0[3]);
    pk[1] = pack4(w1[0], w1[1], w1[2], w1[3]);
    pk[2] = pack4(w2[0], w2[1], w2[2], w2[3]);
    pk[3] = pack4(w3[0], w3[1], w3[2], w3[3]);
    ((i32x4*)Bq)[idx] = pk;
}

// ---- pass 0c: transpose scales [O][G] -> scT [G][O] ----
__global__ __launch_bounds__(256) void prep_sc_kernel(
    const float* __restrict__ scales, float* __restrict__ scT)
{
    const int idx = blockIdx.x * 256 + threadIdx.x;
    const int g = idx / OUT_DIM;
    const int o = idx - g * OUT_DIM;
    scT[idx] = scales[o * NGROUPS + g];
}

// ---- 128x128 i8 GEMM, 32x32x32 MFMA, 64x64 per-wave, 2 blocks/CU ----
// LDS swizzle: slot s of row r holds global 16B granule s ^ SW(r),
// SW(r) = (r&7) ^ ((r>>3)&3).  The (r>>3)&3 term spreads stride-8 lane sets
// (the HW's b128 phase grouping) across 4 granule slots -> 2-way max (free).
__global__ __launch_bounds__(THREADS, 2) void awq_gemm_i8(
    const char* __restrict__ Aq, const char* __restrict__ Bq,
    const float* __restrict__ scT, const float* __restrict__ sx,
    const float* __restrict__ bias, float* __restrict__ out)
{
    // per-XCD block map (rb&7 -> XCD round-robin)
    const int rb = blockIdx.x;                  // grid 1408 = 8 * 176
    const int bm = (rb >> 3) & 15;              // 0..15
    const int bn = (((rb >> 3) >> 4) << 3) + (rb & 7);  // 0..87
    if (bn >= OUT_DIM / BN) return;             // 32 dead pad blocks

    __shared__ char smem[2 * BUFB];             // 64 KB -> 2 blocks/CU
    as3c* ldsb = (as3c*)smem;
    const unsigned lbase = (unsigned)(size_t)ldsb;

    const int tid  = threadIdx.x;
    const int lane = tid & 63;
    const int w    = tid >> 6;        // wave 0..3
    const int wr   = w >> 1;          // 0..1 (M: 2 x 64)
    const int wc   = w & 1;           // 0..1 (N: 2 x 64)
    const int lr   = lane & 31;       // frag row (A) / col (B)
    const int hi   = lane >> 5;       // k-half within 32-elem k-chunk
    const int sw   = (lr & 7) ^ ((lr >> 3) & 3);   // SW(row), uniform per 32-row chunk

    // per-kk swizzled ds_read bases (buffer 0)
    const unsigned aRow = lbase + (unsigned)((wr * 64 + lr) * 128);
    const unsigned bRow = lbase + BOFF + (unsigned)((wc * 64 + lr) * 128);
    const unsigned aS0 = aRow + (unsigned)(((0 + hi) ^ sw) * 16);
    const unsigned aS1 = aRow + (unsigned)(((2 + hi) ^ sw) * 16);
    const unsigned aS2 = aRow + (unsigned)(((4 + hi) ^ sw) * 16);
    const unsigned aS3 = aRow + (unsigned)(((6 + hi) ^ sw) * 16);
    const unsigned bS0 = bRow + (unsigned)(((0 + hi) ^ sw) * 16);
    const unsigned bS1 = bRow + (unsigned)(((2 + hi) ^ sw) * 16);
    const unsigned bS2 = bRow + (unsigned)(((4 + hi) ^ sw) * 16);
    const unsigned bS3 = bRow + (unsigned)(((6 + hi) ^ sw) * 16);

    // staging: thread -> row tid>>3 (0..31) per sweep, granule tid&7 pre-swizzled
    const int srow = tid >> 3;
    const int sg   = (((tid & 7) ^ (srow & 7) ^ ((srow >> 3) & 3))) * 16;
    const char* aSrc = Aq + (size_t)(bm * BM + srow) * IN_DIM + sg;
    const char* bSrc = Bq + (size_t)(bn * BN + srow) * IN_DIM + sg;

    // scale source: per-lane column; +32 floats for j=1
    const float* scp = scT + bn * BN + wc * 64 + lr;

#define STG_A(Q, SRC, P) __builtin_amdgcn_global_load_lds( \
    (const __attribute__((address_space(1))) void*)(const void*)((SRC) + (size_t)((Q) * 32) * IN_DIM), \
    (__attribute__((address_space(3))) void*)(ldsb + (P) * BUFB + (Q) * 4096 + tid * 16), 16, 0, 0)
#define STG_B(Q, SRC, P) __builtin_amdgcn_global_load_lds( \
    (const __attribute__((address_space(1))) void*)(const void*)((SRC) + (size_t)((Q) * 32) * IN_DIM), \
    (__attribute__((address_space(3))) void*)(ldsb + (P) * BUFB + BOFF + (Q) * 4096 + tid * 16), 16, 0, 0)

#define SCV(D0, D1, PTR) do { \
    asm volatile("global_load_dword %0, %1, off" : "=v"(D0) : "v"(PTR)); \
    asm volatile("global_load_dword %0, %1, off" : "=v"(D1) : "v"((PTR) + 32)); \
    SB0; } while (0)

    float accf[2][2][16];
    #pragma unroll
    for (int i = 0; i < 2; ++i)
        #pragma unroll
        for (int j = 0; j < 2; ++j)
            #pragma unroll
            for (int e = 0; e < 16; ++e) accf[i][j][e] = 0.f;

    i32x16 acc[2][2];
    const i32x16 Z = {0,0,0,0,0,0,0,0,0,0,0,0,0,0,0,0};

    float c0, c1, n0 = 0.f, n1 = 0.f, p0 = 0.f, p1 = 0.f;

    // prologue ledger: S0[8], V0[2], S1[8] -> WAITV(8) retires S0+V0, keeps S1
    STG_A(0, aSrc, 0); STG_A(1, aSrc, 0); STG_A(2, aSrc, 0); STG_A(3, aSrc, 0);
    STG_B(0, bSrc, 0); STG_B(1, bSrc, 0); STG_B(2, bSrc, 0); STG_B(3, bSrc, 0);
    SCV(c0, c1, scp);
    STG_A(0, aSrc + BKB, 1); STG_A(1, aSrc + BKB, 1); STG_A(2, aSrc + BKB, 1); STG_A(3, aSrc + BKB, 1);
    STG_B(0, bSrc + BKB, 1); STG_B(1, bSrc + BKB, 1); STG_B(2, bSrc + BKB, 1); STG_B(3, bSrc + BKB, 1);
    WAITV(8);
    __builtin_amdgcn_s_barrier();
    SB0;

    const char* aStg = aSrc + 2 * BKB;   // staging column for tile t+2
    const char* bStg = bSrc + 2 * BKB;
    const float* scN = scp + OUT_DIM;    // scales for group t+1

    for (int t = 0; t < NKT; ++t) {
        const unsigned po = (unsigned)((t & 1) * BUFB);
        i32x4 a[2][4], b[2][4];
        const unsigned pa0 = aS0 + po, pa1 = aS1 + po, pa2 = aS2 + po, pa3 = aS3 + po;
        const unsigned pb0 = bS0 + po, pb1 = bS1 + po, pb2 = bS2 + po, pb3 = bS3 + po;
        // 16 ds_reads of tile t from buf P, kk-major (4 per kk group)
        LDSRO(a[0][0], pa0, 0); LDSRO(a[1][0], pa0, 4096);
        LDSRO(b[0][0], pb0, 0); LDSRO(b[1][0], pb0, 4096);
        LDSRO(a[0][1], pa1, 0); LDSRO(a[1][1], pa1, 4096);
        LDSRO(b[0][1], pb1, 0); LDSRO(b[1][1], pb1, 4096);
        LDSRO(a[0][2], pa2, 0); LDSRO(a[1][2], pa2, 4096);
        LDSRO(b[0][2], pb2, 0); LDSRO(b[1][2], pb2, 4096);
        LDSRO(a[0][3], pa3, 0); LDSRO(a[1][3], pa3, 4096);
        LDSRO(b[0][3], pb3, 0); LDSRO(b[1][3], pb3, 4096);

        // deferred dequant-accumulate of tile t-1: VALU overlaps the reads above
        if (t > 0) {
            #pragma unroll
            for (int i = 0; i < 2; ++i)
                #pragma unroll
                for (int e = 0; e < 16; ++e) {
                    accf[i][0][e] += (float)acc[i][0][e] * p0;
                    accf[i][1][e] += (float)acc[i][1][e] * p1;
                }
        }

        __builtin_amdgcn_s_setprio(1);
        WAITL(12);   // kk0 reads landed
        acc[0][0] = __builtin_amdgcn_mfma_i32_32x32x32_i8(a[0][0], b[0][0], Z, 0, 0, 0);
        acc[0][1] = __builtin_amdgcn_mfma_i32_32x32x32_i8(a[0][0], b[1][0], Z, 0, 0, 0);
        acc[1][0] = __builtin_amdgcn_mfma_i32_32x32x32_i8(a[1][0], b[0][0], Z, 0, 0, 0);
        acc[1][1] = __builtin_amdgcn_mfma_i32_32x32x32_i8(a[1][0], b[1][0], Z, 0, 0, 0);
        WAITL(8);    // kk1
        acc[0][0] = __builtin_amdgcn_mfma_i32_32x32x32_i8(a[0][1], b[0][1], acc[0][0], 0, 0, 0);
        acc[0][1] = __builtin_amdgcn_mfma_i32_32x32x32_i8(a[0][1], b[1][1], acc[0][1], 0, 0, 0);
        acc[1][0] = __builtin_amdgcn_mfma_i32_32x32x32_i8(a[1][1], b[0][1], acc[1][0], 0, 0, 0);
        acc[1][1] = __builtin_amdgcn_mfma_i32_32x32x32_i8(a[1][1], b[1][1], acc[1][1], 0, 0, 0);
        WAITL(4);    // kk2
        acc[0][0] = __builtin_amdgcn_mfma_i32_32x32x32_i8(a[0][2], b[0][2], acc[0][0], 0, 0, 0);
        acc[0][1] = __builtin_amdgcn_mfma_i32_32x32x32_i8(a[0][2], b[1][2], acc[0][1], 0, 0, 0);
        acc[1][0] = __builtin_amdgcn_mfma_i32_32x32x32_i8(a[1][2], b[0][2], acc[1][0], 0, 0, 0);
        acc[1][1] = __builtin_amdgcn_mfma_i32_32x32x32_i8(a[1][2], b[1][2], acc[1][1], 0, 0, 0);
        WAITL(0);    // all 16 reads done for THIS wave
        __builtin_amdgcn_s_barrier();   // all waves done reading buf P -> safe to restage it
        SB0;
        acc[0][0] = __builtin_amdgcn_mfma_i32_32x32x32_i8(a[0][3], b[0][3], acc[0][0], 0, 0, 0);
        acc[0][1] = __builtin_amdgcn_mfma_i32_32x32x32_i8(a[0][3], b[1][3], acc[0][1], 0, 0, 0);
        acc[1][0] = __builtin_amdgcn_mfma_i32_32x32x32_i8(a[1][3], b[0][3], acc[1][0], 0, 0, 0);
        acc[1][1] = __builtin_amdgcn_mfma_i32_32x32x32_i8(a[1][3], b[1][3], acc[1][1], 0, 0, 0);
        __builtin_amdgcn_s_setprio(0);

        // prefetch next-group scales, then stage tile t+2 into the freed buf P
        const bool haveN = (t + 1 < NKT);
        if (haveN) SCV(n0, n1, scN);
        if (t + 2 < NKT) {
            STG_A(0, aStg, (t & 1)); STG_A(1, aStg, (t & 1)); STG_A(2, aStg, (t & 1)); STG_A(3, aStg, (t & 1));
            STG_B(0, bStg, (t & 1)); STG_B(1, bStg, (t & 1)); STG_B(2, bStg, (t & 1)); STG_B(3, bStg, (t & 1));
        }
        aStg += BKB; bStg += BKB; scN += OUT_DIM;

        // gate: steady state retires S(t+1)[8]+V(t+1)[2], keeps S(t+2)[8]
        if (t < NKT - 2) { WAITV(8); } else { WAITV(0); }
        __builtin_amdgcn_s_barrier();
        SB0;
        p0 = c0; p1 = c1;                  // scales for the now-pending tile t
        if (haveN) { c0 = n0; c1 = n1; }   // V(t+1) retired at the gate
    }

    // final dequant-accumulate (tile NKT-1)
    #pragma unroll
    for (int i = 0; i < 2; ++i)
        #pragma unroll
        for (int e = 0; e < 16; ++e) {
            accf[i][0][e] += (float)acc[i][0][e] * p0;
            accf[i][1][e] += (float)acc[i][1][e] * p1;
        }

    // ---- epilogue: * sx[row], + bias[col] ----
    // C/D 32x32 layout: col = lane&31, row = (reg&3) + 8*(reg>>2) + 4*(lane>>5)
    const int colBase = bn * BN + wc * 64 + lr;
    const float bv0 = bias[colBase];
    const float bv1 = bias[colBase + 32];
    #pragma unroll
    for (int i = 0; i < 2; ++i) {
        #pragma unroll
        for (int q = 0; q < 4; ++q) {
            const int r0 = bm * BM + wr * 64 + i * 32 + q * 8 + hi * 4;
            const f32x4 sxv = *(const f32x4*)(sx + r0);
            #pragma unroll
            for (int e = 0; e < 4; ++e) {
                out[(size_t)(r0 + e) * OUT_DIM + colBase]      = accf[i][0][q * 4 + e] * sxv[e] + bv0;
                out[(size_t)(r0 + e) * OUT_DIM + colBase + 32] = accf[i][1][q * 4 + e] * sxv[e] + bv1;
            }
        }
    }

#undef STG_A
#undef STG_B
#undef SCV
}

// ---- fallback (no workspace): round-1 proven kernel ----
__global__ __launch_bounds__(256) void awq_gemm_fb(
    const float* __restrict__ x, const int* __restrict__ wq,
    const float* __restrict__ scales, const float* __restrict__ s,
    const float* __restrict__ bias, float* __restrict__ out)
{
    __shared__ short As[128][32];
    __shared__ short Bs[128][32];
    const int tid = threadIdx.x, lane = tid & 63, wave = tid >> 6;
    const int nbn = OUT_DIM / 128;
    const int bm = blockIdx.x / nbn, bn = blockIdx.x % nbn;
    const int srow = tid >> 1, scol = (tid & 1) * 16;
    const int wm = (wave >> 1) * 64, wn = (wave & 1) * 64;
    f32x4 acc[4][4];
    #pragma unroll
    for (int i = 0; i < 4; ++i)
        #pragma unroll
        for (int j = 0; j < 4; ++j) acc[i][j] = (f32x4){0.f, 0.f, 0.f, 0.f};
    const float* xrow = x + (size_t)(bm * 128 + srow) * IN_DIM;
    const int* wrow = wq + (size_t)(bn * 128 + srow) * IN_DIM;
    const float* scrow = scales + (size_t)(bn * 128 + srow) * NGROUPS;
    const int fr = lane & 15, fk = (lane >> 4) * 8, fq = lane >> 4;
    for (int kt = 0; kt < IN_DIM / 32; ++kt) {
        const int k0 = kt * 32;
        {
            const float* xp = xrow + k0 + scol;
            const float* sp = s + k0 + scol;
            short tmp[16];
            #pragma unroll
            for (int q = 0; q < 4; ++q) {
                f32x4 xv = *(const f32x4*)(xp + q * 4);
                f32x4 sv = *(const f32x4*)(sp + q * 4);
                #pragma unroll
                for (int e = 0; e < 4; ++e) tmp[q * 4 + e] = f2bf(xv[e] / sv[e]);
            }
            #pragma unroll
            for (int e = 0; e < 16; ++e) As[srow][scol + e] = tmp[e];
        }
        {
            const float sc = scrow[kt >> 2];
            const int* wp = wrow + k0 + scol;
            short tmp[16];
            #pragma unroll
            for (int q = 0; q < 4; ++q) {
                i32x4 wv = *(const i32x4*)(wp + q * 4);
                #pragma unroll
                for (int e = 0; e < 4; ++e) tmp[q * 4 + e] = f2bf((float)wv[e] * sc);
            }
            #pragma unroll
            for (int e = 0; e < 16; ++e) Bs[srow][scol + e] = tmp[e];
        }
        __syncthreads();
        bf16x8 a[4], b[4];
        #pragma unroll
        for (int i = 0; i < 4; ++i) a[i] = *(const bf16x8*)&As[wm + i * 16 + fr][fk];
        #pragma unroll
        for (int j = 0; j < 4; ++j) b[j] = *(const bf16x8*)&Bs[wn + j * 16 + fr][fk];
        #pragma unroll
        for (int i = 0; i < 4; ++i)
            #pragma unroll
            for (int j = 0; j < 4; ++j)
                acc[i][j] = __builtin_amdgcn_mfma_f32_16x16x32_bf16(a[i], b[j], acc[i][j], 0, 0, 0);
        __syncthreads();
    }
    #pragma unroll
    for (int i = 0; i < 4; ++i) {
        const int row = bm * 128 + wm + i * 16 + fq * 4;
        #pragma unroll
        for (int j = 0; j < 4; ++j) {
            const int col = bn * 128 + wn + j * 16 + fr;
            const float bv = bias[col];
            #pragma unroll
            for (int e = 0; e < 4; ++e)
                out[(size_t)(row + e) * OUT_DIM + col] = acc[i][j][e] + bv;
        }
    }
}

extern "C" void kernel_launch(void* const* d_in, const int* in_sizes, int n_in,
                              void* d_out, int out_size, void* d_ws, size_t ws_size,
                              hipStream_t stream) {
    const float* x      = (const float*)d_in[0];
    const int*   wq     = (const int*)  d_in[1];
    const float* scales = (const float*)d_in[2];
    const float* s      = (const float*)d_in[3];
    const float* bias   = (const float*)d_in[4];
    float* out = (float*)d_out;

    // ws layout (16B-aligned): Aq 8MB | sx 8KB | Bq 43MB | scT 1.4MB
    const size_t off_sx = (size_t)TOKENS * IN_DIM;             // 8388608
    const size_t off_bq = off_sx + 8192;
    const size_t off_sc = off_bq + (size_t)OUT_DIM * IN_DIM;
    const size_t need   = off_sc + (size_t)OUT_DIM * NGROUPS * 4;  // ~54.9MB

    if (ws_size >= need) {
        char*  Aq  = (char*)d_ws;
        float* sxw = (float*)((char*)d_ws + off_sx);
        char*  Bq  = (char*)d_ws + off_bq;
        float* scT = (float*)((char*)d_ws + off_sc);
        prep_a_kernel<<<TOKENS, 256, 0, stream>>>(x, s, Aq, sxw);
        prep_b_kernel<<<OUT_DIM * IN_DIM / 16 / 256, 256, 0, stream>>>(wq, Bq);
        prep_sc_kernel<<<OUT_DIM * NGROUPS / 256, 256, 0, stream>>>(scales, scT);
        awq_gemm_i8<<<1408, THREADS, 0, stream>>>(Aq, Bq, scT, sxw, bias, out);
    } else {
        awq_gemm_fb<<<(TOKENS / 128) * (OUT_DIM / 128), 256, 0, stream>>>(x, wq, scales, s, bias, out);
    }
}